// Round 1
// baseline (520.755 us; speedup 1.0000x reference)
//
#include <hip/hip_runtime.h>

#define NB 32
#define CH 256
#define HH 56
#define WW 56
#define WQ_ELEMS (CH*CH*3*3)   // 589824

typedef short short8 __attribute__((ext_vector_type(8)));
typedef float f32x4 __attribute__((ext_vector_type(4)));

__device__ __forceinline__ unsigned short f2bf(float f) {
  unsigned u = __builtin_bit_cast(unsigned, f);
  u += 0x7FFFu + ((u >> 16) & 1u);   // round-to-nearest-even
  return (unsigned short)(u >> 16);
}

// ---------------- kernel 1: max(|w|) ----------------
__global__ void absmax_kernel(const float* __restrict__ w, unsigned* __restrict__ out) {
  int tid = blockIdx.x * 256 + threadIdx.x;
  float v = (tid < WQ_ELEMS) ? fabsf(w[tid]) : 0.f;
  #pragma unroll
  for (int o = 32; o > 0; o >>= 1) v = fmaxf(v, __shfl_xor(v, o, 64));
  if ((threadIdx.x & 63) == 0) atomicMax(out, __builtin_bit_cast(unsigned, v));
}

// ---------------- kernel 2: ternary quantize -> bf16, layout [k][oc][ic] ----------------
__global__ void quant_kernel(const float* __restrict__ w, const float* __restrict__ Wp,
                             const float* __restrict__ Wn, const unsigned* __restrict__ mx,
                             unsigned short* __restrict__ wq) {
  int tid = blockIdx.x * 256 + threadIdx.x;
  if (tid >= WQ_ELEMS) return;
  float m = __builtin_bit_cast(float, *mx);
  float thr = 0.05f * m;
  float v = w[tid];
  float q = 0.f;
  if (m > 0.f) {
    if (v > thr) q = Wp[0];
    else if (v < -thr) q = -Wn[0];
  }
  // input linear: [oc][ic][kh][kw]
  int oc  = tid / (CH * 9);
  int rem = tid - oc * (CH * 9);
  int ic  = rem / 9;
  int k   = rem - ic * 9;          // kh*3+kw
  wq[(k * CH + oc) * CH + ic] = f2bf(q);
}

// ---------------- kernel 3: conv as per-tap MFMA GEMM ----------------
#define ICB  32      // ic chunk (one MFMA K)
#define WLP  40      // padded LDS row in shorts (32 + 8)
#define XROWS 66     // w index range: w(0..63) + kw(0..2) - 1, shifted by +1

__global__ __launch_bounds__(512)
void conv_kernel(const float* __restrict__ x, const unsigned short* __restrict__ wq,
                 const float* __restrict__ bias, float* __restrict__ out) {
  __shared__ __align__(16) unsigned short Wl[3][256][WLP];   // [kw][oc][ic]
  __shared__ __align__(16) unsigned short Xl[2][XROWS][WLP]; // [row][w+1][ic]

  const int tid  = threadIdx.x;
  const int lane = tid & 63;
  const int wid  = tid >> 6;     // 0..7
  const int wrow = wid >> 2;     // which of the 2 output rows
  const int wm   = wid & 3;      // oc quarter (64 oc each)
  const int n    = blockIdx.x;
  const int h0   = blockIdx.y * 2;

  const int l15 = lane & 15;
  const int lg  = lane >> 4;     // 0..3 (k-group)

  f32x4 acc[4][4];
  #pragma unroll
  for (int i = 0; i < 4; ++i)
    #pragma unroll
    for (int j = 0; j < 4; ++j) acc[i][j] = (f32x4)0.f;

  for (int ic0 = 0; ic0 < CH; ic0 += ICB) {
    for (int kh = 0; kh < 3; ++kh) {
      __syncthreads();
      // ---- stage weights for this (kh, ic-chunk): 3 kw * 256 oc * 32 ic shorts = 3072 x 16B
      #pragma unroll
      for (int i = 0; i < 6; ++i) {
        int c   = tid + 512 * i;       // 0..3071
        int kw  = c >> 10;             // 1024 chunks per kw
        int rem = c & 1023;
        int oc  = rem >> 2;
        int icg = rem & 3;
        const int4* src = (const int4*)(wq + (((kh * 3 + kw) * CH + oc) * CH + ic0 + icg * 8));
        *(int4*)&Wl[kw][oc][icg * 8] = *src;
      }
      // ---- stage x rows (convert f32 -> bf16, transpose to [w][ic])
      for (int idx = tid; idx < 2 * XROWS * ICB; idx += 512) {
        int wpos = idx % XROWS;
        int t    = idx / XROWS;        // 0..63
        int ic   = t & 31;
        int r    = t >> 5;
        int hx   = h0 + r + kh - 1;
        int xw   = wpos - 1;
        float v = 0.f;
        if ((unsigned)hx < 56u && (unsigned)xw < 56u)
          v = x[((n * CH + ic0 + ic) * HH + hx) * WW + xw];
        Xl[r][wpos][ic] = f2bf(v);
      }
      __syncthreads();
      // ---- compute: per kw, 4x4 fragment tile per wave
      #pragma unroll
      for (int kw = 0; kw < 3; ++kw) {
        short8 a[4];
        #pragma unroll
        for (int m = 0; m < 4; ++m)
          a[m] = *(const short8*)&Wl[kw][wm * 64 + m * 16 + l15][lg * 8];
        #pragma unroll
        for (int nb = 0; nb < 4; ++nb) {
          short8 b = *(const short8*)&Xl[wrow][nb * 16 + l15 + kw][lg * 8];
          #pragma unroll
          for (int m = 0; m < 4; ++m)
            acc[m][nb] = __builtin_amdgcn_mfma_f32_16x16x32_bf16(a[m], b, acc[m][nb], 0, 0, 0);
        }
      }
    }
  }

  // ---- epilogue: D col = lane&15 (w), row = (lane>>4)*4 + r (oc)
  const int h = h0 + wrow;
  #pragma unroll
  for (int m = 0; m < 4; ++m) {
    int oc = wm * 64 + m * 16 + lg * 4;
    #pragma unroll
    for (int nb = 0; nb < 4; ++nb) {
      int w = nb * 16 + l15;
      if (w < 56) {
        #pragma unroll
        for (int r = 0; r < 4; ++r)
          out[((n * CH + oc + r) * HH + h) * WW + w] = acc[m][nb][r] + bias[oc + r];
      }
    }
  }
}

extern "C" void kernel_launch(void* const* d_in, const int* in_sizes, int n_in,
                              void* d_out, int out_size, void* d_ws, size_t ws_size,
                              hipStream_t stream) {
  const float* x      = (const float*)d_in[0];
  const float* weight = (const float*)d_in[1];
  const float* bias   = (const float*)d_in[2];
  const float* Wp     = (const float*)d_in[3];
  const float* Wn     = (const float*)d_in[4];
  float* out          = (float*)d_out;

  unsigned* mx        = (unsigned*)d_ws;
  unsigned short* wqp = (unsigned short*)((char*)d_ws + 64);

  // zero the max accumulator (ws is poisoned, atomicMax needs 0 init; deterministic)
  hipMemsetAsync(d_ws, 0, 64, stream);

  absmax_kernel<<<(WQ_ELEMS + 255) / 256, 256, 0, stream>>>(weight, mx);
  quant_kernel<<<(WQ_ELEMS + 255) / 256, 256, 0, stream>>>(weight, Wp, Wn, mx, wqp);
  conv_kernel<<<dim3(NB, HH / 2), 512, 0, stream>>>(x, wqp, bias, out);
}

// Round 2
// 476.447 us; speedup vs baseline: 1.0930x; 1.0930x over previous
//
#include <hip/hip_runtime.h>

#define CH 256
#define HH 56
#define WW 56
#define HWSZ (HH*WW)            // 3136
#define WQ_ELEMS (CH*CH*9)      // 589824

#define XSTRIDE (66*32)         // shorts per x-row plane
#define XBUF (6*XSTRIDE)        // shorts per buffer
#define NCHUNK 1584             // 6 rows * 66 iw * 4 slots

typedef short short8 __attribute__((ext_vector_type(8)));
typedef float f32x4 __attribute__((ext_vector_type(4)));

__device__ __forceinline__ unsigned short f2bf(float f) {
  unsigned u = __builtin_bit_cast(unsigned, f);
  u += 0x7FFFu + ((u >> 16) & 1u);   // round-to-nearest-even
  return (unsigned short)(u >> 16);
}

// ---------------- kernel 1: max(|w|), float4 ----------------
__global__ void absmax_kernel(const float4* __restrict__ w, unsigned* __restrict__ out) {
  int tid = blockIdx.x * 256 + threadIdx.x;       // 147456 total
  float4 v = w[tid];
  float m = fmaxf(fmaxf(fabsf(v.x), fabsf(v.y)), fmaxf(fabsf(v.z), fabsf(v.w)));
  #pragma unroll
  for (int o = 32; o; o >>= 1) m = fmaxf(m, __shfl_xor(m, o, 64));
  if ((threadIdx.x & 63) == 0) atomicMax(out, __builtin_bit_cast(unsigned, m));
}

// ---------------- kernel 2: ternary quantize -> bf16 [k][oc][ic], coalesced writes ----------------
__global__ void quant_kernel(const float* __restrict__ w, const float* __restrict__ Wp,
                             const float* __restrict__ Wn, const unsigned* __restrict__ mx,
                             unsigned short* __restrict__ wq) {
  int o = blockIdx.x * 256 + threadIdx.x;         // 589824
  int ic = o & 255, oc = (o >> 8) & 255, k = o >> 16;
  float m = __builtin_bit_cast(float, *mx);
  float thr = 0.05f * m;
  float v = w[(oc * CH + ic) * 9 + k];
  float q = 0.f;
  if (m > 0.f) {
    if (v > thr) q = Wp[0];
    else if (v < -thr) q = -Wn[0];
  }
  wq[o] = f2bf(q);
}

// ---------------- kernel 3: conv. Block = (n, 4 h rows) x 256 oc x 56 w ----------------
// 8 waves = 4 oc-quarters x 2 row-pairs. Wave tile: 64 oc x 64 w x 2 rows (16x16x32 MFMA).
// X in LDS (dbuf, XOR-swizzled 16B slots); W read global->VGPR (L2-resident).
__global__ __launch_bounds__(512, 2)
void conv_kernel(const float* __restrict__ x, const unsigned short* __restrict__ wq,
                 const float* __restrict__ bias, float* __restrict__ out) {
  __shared__ __align__(16) unsigned short Xl[2 * XBUF];

  const int tid  = threadIdx.x;
  const int lane = tid & 63;
  const int l15  = lane & 15;
  const int kg   = lane >> 4;      // 0..3 (k-group of 8 ic)
  const int wid  = tid >> 6;
  const int wm   = wid & 3;        // oc quarter
  const int wrp  = wid >> 2;       // row pair (rows 2*wrp, 2*wrp+1)
  const int n    = blockIdx.x;
  const int h0   = blockIdx.y * 4;

  f32x4 acc[4][4][2];
  #pragma unroll
  for (int m = 0; m < 4; ++m)
    #pragma unroll
    for (int nc = 0; nc < 4; ++nc)
      #pragma unroll
      for (int rr = 0; rr < 2; ++rr) acc[m][nc][rr] = (f32x4)0.f;

  // ---- precompute per-thread staging chunk geometry (4 chunks max) ----
  const float* gp[4];
  int lds_off[4];
  bool c_exists[4], c_ok[4];
  #pragma unroll
  for (int k = 0; k < 4; ++k) {
    int c = tid + k * 512;
    c_exists[k] = (c < NCHUNK);
    int cc = c_exists[k] ? c : 0;
    int slot = cc & 3;
    int q    = cc >> 2;            // 0..395
    int iw   = q % 66;
    int r    = q / 66;             // 0..5
    int hx = h0 + r - 1;
    int xw = iw - 1;
    c_ok[k] = c_exists[k] && ((unsigned)hx < (unsigned)HH) && ((unsigned)xw < (unsigned)WW);
    gp[k] = x + ((long)(n * CH + slot * 8) * HWSZ + (c_ok[k] ? (hx * WW + xw) : 0));
    lds_off[k] = r * XSTRIDE + iw * 32 + ((slot ^ (iw & 3)) * 8);
  }

  const unsigned short* wbase = wq + (wm * 64 + l15) * CH + kg * 8;

  float xr[4][8];

  // ---- prologue: stage ic-chunk 0 into buffer 0 ----
  #pragma unroll
  for (int k = 0; k < 4; ++k)
    #pragma unroll
    for (int j = 0; j < 8; ++j)
      xr[k][j] = c_ok[k] ? gp[k][j * HWSZ] : 0.f;
  #pragma unroll
  for (int k = 0; k < 4; ++k) {
    if (c_exists[k]) {
      short8 p;
      #pragma unroll
      for (int j = 0; j < 8; ++j) p[j] = (short)f2bf(xr[k][j]);
      *(short8*)&Xl[lds_off[k]] = p;
    }
  }
  __syncthreads();

  for (int t = 0; t < 8; ++t) {
    const int ic0  = t * 32;
    const int bufc = (t & 1) * XBUF;
    const int bufs = ((t + 1) & 1) * XBUF;

    // ---- issue next chunk's global loads early (latency hides under MFMA) ----
    if (t < 7) {
      const int icn = (t + 1) * 32;
      #pragma unroll
      for (int k = 0; k < 4; ++k)
        #pragma unroll
        for (int j = 0; j < 8; ++j)
          xr[k][j] = c_ok[k] ? gp[k][(long)(icn + j) * HWSZ] : 0.f;
    }

    // ---- compute: 9 taps, A from global, B from LDS ----
    #pragma unroll
    for (int kh = 0; kh < 3; ++kh) {
      #pragma unroll
      for (int kw = 0; kw < 3; ++kw) {
        const int s = kh * 3 + kw;
        short8 a[4];
        #pragma unroll
        for (int m = 0; m < 4; ++m)
          a[m] = *(const short8*)(wbase + s * 65536 + m * 4096 + ic0);
        #pragma unroll
        for (int rr = 0; rr < 2; ++rr) {
          const int rx = wrp * 2 + rr + kh;     // 0..5
          #pragma unroll
          for (int nc = 0; nc < 4; ++nc) {
            const int iw = nc * 16 + l15 + kw;  // 0..65
            short8 b = *(const short8*)&Xl[bufc + rx * XSTRIDE + iw * 32 + ((kg ^ (iw & 3)) * 8)];
            #pragma unroll
            for (int m = 0; m < 4; ++m)
              acc[m][nc][rr] = __builtin_amdgcn_mfma_f32_16x16x32_bf16(a[m], b, acc[m][nc][rr], 0, 0, 0);
          }
        }
      }
    }

    // ---- write staged chunk to the other buffer ----
    if (t < 7) {
      #pragma unroll
      for (int k = 0; k < 4; ++k) {
        if (c_exists[k]) {
          short8 p;
          #pragma unroll
          for (int j = 0; j < 8; ++j) p[j] = (short)f2bf(xr[k][j]);
          *(short8*)&Xl[bufs + lds_off[k]] = p;
        }
      }
    }
    __syncthreads();
  }

  // ---- epilogue: D col = lane&15 (w), row = kg*4 + j (oc) ----
  #pragma unroll
  for (int rr = 0; rr < 2; ++rr) {
    const int h = h0 + wrp * 2 + rr;
    #pragma unroll
    for (int nc = 0; nc < 4; ++nc) {
      const int w = nc * 16 + l15;
      if (w < WW) {
        #pragma unroll
        for (int m = 0; m < 4; ++m) {
          const int oc = wm * 64 + m * 16 + kg * 4;
          float* op = out + ((long)(n * CH + oc) * HH + h) * WW + w;
          #pragma unroll
          for (int j = 0; j < 4; ++j)
            op[(long)j * HWSZ] = acc[m][nc][rr][j] + bias[oc + j];
        }
      }
    }
  }
}

extern "C" void kernel_launch(void* const* d_in, const int* in_sizes, int n_in,
                              void* d_out, int out_size, void* d_ws, size_t ws_size,
                              hipStream_t stream) {
  const float* x      = (const float*)d_in[0];
  const float* weight = (const float*)d_in[1];
  const float* bias   = (const float*)d_in[2];
  const float* Wp     = (const float*)d_in[3];
  const float* Wn     = (const float*)d_in[4];
  float* out          = (float*)d_out;

  unsigned* mx        = (unsigned*)d_ws;
  unsigned short* wqp = (unsigned short*)((char*)d_ws + 64);

  hipMemsetAsync(d_ws, 0, 64, stream);
  absmax_kernel<<<WQ_ELEMS / 4 / 256, 256, 0, stream>>>((const float4*)weight, mx);
  quant_kernel<<<WQ_ELEMS / 256, 256, 0, stream>>>(weight, Wp, Wn, mx, wqp);
  conv_kernel<<<dim3(32, HH / 4), 512, 0, stream>>>(x, wqp, bias, out);
}

// Round 3
// 396.892 us; speedup vs baseline: 1.3121x; 1.2004x over previous
//
#include <hip/hip_runtime.h>

#define CH 256
#define HH 56
#define WW 56
#define HWSZ (HH*WW)            // 3136
#define WQ_ELEMS (CH*CH*9)      // 589824

#define IWN 66                  // staged iw positions (covers nc*16+l15+kw)
#define XROW (IWN*32)           // shorts per input-row plane = 2112
#define XBUF (6*XROW)           // 12672 shorts per buffer
#define NCHUNK (6*IWN*4)        // 1584 staging chunks (row, iw, 8-ic slot)

typedef short short8 __attribute__((ext_vector_type(8)));
typedef float f32x4 __attribute__((ext_vector_type(4)));

__device__ __forceinline__ unsigned short f2bf(float f) {
  unsigned u = __builtin_bit_cast(unsigned, f);
  u += 0x7FFFu + ((u >> 16) & 1u);   // round-to-nearest-even
  return (unsigned short)(u >> 16);
}

// ---------------- kernel 1: max(|w|), float4 ----------------
__global__ void absmax_kernel(const float4* __restrict__ w, unsigned* __restrict__ out) {
  int tid = blockIdx.x * 256 + threadIdx.x;       // 147456 total
  float4 v = w[tid];
  float m = fmaxf(fmaxf(fabsf(v.x), fabsf(v.y)), fmaxf(fabsf(v.z), fabsf(v.w)));
  #pragma unroll
  for (int o = 32; o; o >>= 1) m = fmaxf(m, __shfl_xor(m, o, 64));
  if ((threadIdx.x & 63) == 0) atomicMax(out, __builtin_bit_cast(unsigned, m));
}

// ---------------- kernel 2: quantize -> bf16, layout [tap][ic-chunk][oc][32ic] ----------------
// offset = tap*65536 + chunk*8192 + oc*32 + ic2  -> A-loads become 1KB fully-coalesced per wave
__global__ void quant_kernel(const float* __restrict__ w, const float* __restrict__ Wp,
                             const float* __restrict__ Wn, const unsigned* __restrict__ mx,
                             unsigned short* __restrict__ wq) {
  int o = blockIdx.x * 256 + threadIdx.x;         // 589824
  int ic2 = o & 31, oc = (o >> 5) & 255, c = (o >> 13) & 7, k = o >> 16;
  int ic = c * 32 + ic2;
  float m = __builtin_bit_cast(float, *mx);
  float thr = 0.05f * m;
  float v = w[(oc * CH + ic) * 9 + k];
  float q = 0.f;
  if (m > 0.f) {
    if (v > thr) q = Wp[0];
    else if (v < -thr) q = -Wn[0];
  }
  wq[o] = f2bf(q);
}

// ---------------- kernel 3: conv ----------------
// Block = (n, 4 output rows) x 256 oc x 56 w. 16 waves = 4 oc-quarters x 4 rows.
// Wave tile 64oc x 64w x 1 row -> acc = 64 VGPR (no spill at 128 budget).
// X in LDS (6 input rows, dbuf over ic-chunks, XOR-swizzled); W global->VGPR (L2).
__global__ __launch_bounds__(1024, 1)
void conv_kernel(const float* __restrict__ x, const unsigned short* __restrict__ wq,
                 const float* __restrict__ bias, float* __restrict__ out) {
  __shared__ __align__(16) unsigned short Xl[2 * XBUF];   // 50.7 KB

  const int tid  = threadIdx.x;
  const int lane = tid & 63;
  const int l15  = lane & 15;
  const int kg   = lane >> 4;      // 0..3
  const int wid  = tid >> 6;       // 0..15
  const int wm   = wid & 3;        // oc quarter
  const int wr   = wid >> 2;       // output row 0..3
  const int n    = blockIdx.x;
  const int h0   = blockIdx.y * 4;

  f32x4 acc[4][4];
  #pragma unroll
  for (int m = 0; m < 4; ++m)
    #pragma unroll
    for (int nc = 0; nc < 4; ++nc) acc[m][nc] = (f32x4)0.f;

  // ---- staging geometry: chunk c = (row r, iw, 8-ic slot); thread owns c=tid (+1024) ----
  const float* gp[2];
  int  lds_off[2];
  bool ok[2], ex[2];
  #pragma unroll
  for (int k = 0; k < 2; ++k) {
    int c = tid + k * 1024;
    ex[k] = (c < NCHUNK);
    int cc   = ex[k] ? c : 0;
    int slot = cc & 3;
    int q    = cc >> 2;            // 0..395
    int iw   = q % IWN;
    int r    = q / IWN;            // 0..5
    int hx = h0 + r - 1;
    int xw = iw - 1;
    ok[k] = ex[k] && ((unsigned)hx < (unsigned)HH) && ((unsigned)xw < (unsigned)WW);
    gp[k] = x + (long)(n * CH + slot * 8) * HWSZ + (ok[k] ? (hx * WW + xw) : 0);
    lds_off[k] = r * XROW + iw * 32 + ((slot ^ (iw & 3)) * 8);
  }

  float xr[2][8];

  // ---- prologue: stage ic-chunk 0 into buffer 0 ----
  #pragma unroll
  for (int k = 0; k < 2; ++k)
    #pragma unroll
    for (int j = 0; j < 8; ++j)
      xr[k][j] = ok[k] ? gp[k][j * HWSZ] : 0.f;
  #pragma unroll
  for (int k = 0; k < 2; ++k) {
    if (ex[k]) {
      short8 p;
      #pragma unroll
      for (int j = 0; j < 8; ++j) p[j] = (short)f2bf(xr[k][j]);
      *(short8*)&Xl[lds_off[k]] = p;
    }
  }
  __syncthreads();

  for (int t = 0; t < 8; ++t) {
    const int cur = (t & 1) * XBUF;
    const int nxt = ((t + 1) & 1) * XBUF;

    // ---- issue next ic-chunk's global loads early (land under MFMA) ----
    if (t < 7) {
      const int icn = (t + 1) * 32;
      #pragma unroll
      for (int k = 0; k < 2; ++k)
        #pragma unroll
        for (int j = 0; j < 8; ++j)
          xr[k][j] = ok[k] ? gp[k][(icn + j) * HWSZ] : 0.f;
    }

    // ---- compute: 9 taps; A coalesced from global (L2-resident), B from LDS ----
    #pragma unroll
    for (int kh = 0; kh < 3; ++kh) {
      const int rx = wr + kh;      // LDS input-row index 0..5
      #pragma unroll
      for (int kw = 0; kw < 3; ++kw) {
        const int s = kh * 3 + kw;
        short8 a[4];
        #pragma unroll
        for (int m = 0; m < 4; ++m)
          a[m] = *(const short8*)(wq + (s * 8 + t) * 8192 + (wm * 64 + m * 16 + l15) * 32 + kg * 8);
        #pragma unroll
        for (int nc = 0; nc < 4; ++nc) {
          const int iw = nc * 16 + l15 + kw;
          short8 b = *(const short8*)&Xl[cur + rx * XROW + iw * 32 + ((kg ^ (iw & 3)) * 8)];
          #pragma unroll
          for (int m = 0; m < 4; ++m)
            acc[m][nc] = __builtin_amdgcn_mfma_f32_16x16x32_bf16(a[m], b, acc[m][nc], 0, 0, 0);
        }
      }
    }

    // ---- write staged chunk to the other buffer; one barrier per ic-chunk ----
    if (t < 7) {
      #pragma unroll
      for (int k = 0; k < 2; ++k) {
        if (ex[k]) {
          short8 p;
          #pragma unroll
          for (int j = 0; j < 8; ++j) p[j] = (short)f2bf(xr[k][j]);
          *(short8*)&Xl[nxt + lds_off[k]] = p;
        }
      }
    }
    __syncthreads();
  }

  // ---- epilogue: D col = l15 (w), row = kg*4 + j (oc) ----
  const int h = h0 + wr;
  #pragma unroll
  for (int m = 0; m < 4; ++m) {
    const int oc = wm * 64 + m * 16 + kg * 4;
    #pragma unroll
    for (int nc = 0; nc < 4; ++nc) {
      const int w = nc * 16 + l15;
      if (w < WW) {
        float* op = out + ((long)(n * CH + oc) * HH + h) * WW + w;
        #pragma unroll
        for (int j = 0; j < 4; ++j)
          op[(long)j * HWSZ] = acc[m][nc][j] + bias[oc + j];
      }
    }
  }
}

extern "C" void kernel_launch(void* const* d_in, const int* in_sizes, int n_in,
                              void* d_out, int out_size, void* d_ws, size_t ws_size,
                              hipStream_t stream) {
  const float* x      = (const float*)d_in[0];
  const float* weight = (const float*)d_in[1];
  const float* bias   = (const float*)d_in[2];
  const float* Wp     = (const float*)d_in[3];
  const float* Wn     = (const float*)d_in[4];
  float* out          = (float*)d_out;

  unsigned* mx        = (unsigned*)d_ws;
  unsigned short* wqp = (unsigned short*)((char*)d_ws + 64);

  hipMemsetAsync(d_ws, 0, 64, stream);
  absmax_kernel<<<WQ_ELEMS / 4 / 256, 256, 0, stream>>>((const float4*)weight, mx);
  quant_kernel<<<WQ_ELEMS / 256, 256, 0, stream>>>(weight, Wp, Wn, mx, wqp);
  conv_kernel<<<dim3(32, HH / 4), 1024, 0, stream>>>(x, wqp, bias, out);
}